// Round 3
// baseline (1126.737 us; speedup 1.0000x reference)
//
#include <hip/hip_runtime.h>
#include <cstdint>
#include <cstddef>

#define B_  8
#define N_  4096   // H*W
#define M_  512    // memory slots
#define D_  512    // feature dim (= C)
#define HW_ 4096

#define FIX_EPS 4e-3f

typedef unsigned short u16;
typedef unsigned int   u32;
typedef short bf8 __attribute__((ext_vector_type(8)));
typedef float f4n __attribute__((ext_vector_type(4)));

__device__ __forceinline__ float bf2f(u16 u) {
  return __uint_as_float(((u32)u) << 16);
}
__device__ __forceinline__ void split_f32(float x, u16& hi, u16& lo) {
  const u32 xb = __float_as_uint(x);
  hi = (u16)(xb >> 16);
  const float hif = __uint_as_float(xb & 0xffff0000u);
  lo = (u16)(__float_as_uint(x - hif) >> 16);
}

// -------- workspace layout (float offsets) --------
// score   : 0          [B,N,M] fp32 (raw; then in-place bf16 hi|lo softmax)
// qf_hi   : 16777216   [B,N,D] u16   qf_lo: 25165824
// qu      : 33554432   [B,M,D] fp32
// inv_nrm : 35651584   [B,N]
// s_at    : 35684352   [B,N]
// colmax  : 35717120   [B,M]
// assign  : 35721216   [B,N] int
// keys_hi : 35753984   keys_lo: 35885056   keysT_hi: 36016128  keysT_lo: 36147200
// fix_cnt : 36278272   (1 int)
// fix_list: 36278273   (32768 int)
// total ~36,311,041 floats = 145.2 MB

// K0: split keys into bf16 hi/lo (+ transposed copies); zero fixup counter
__global__ __launch_bounds__(256) void k_split_keys(
    const float* __restrict__ keys, u16* __restrict__ kh, u16* __restrict__ kl,
    u16* __restrict__ kth, u16* __restrict__ ktl, int* __restrict__ fix_cnt) {
  if (blockIdx.x == 0 && blockIdx.y == 0 && threadIdx.x == 0) *fix_cnt = 0;
  __shared__ float t[32][33];
  const int d0 = blockIdx.x * 32, m0 = blockIdx.y * 32;
  const int tid = threadIdx.x, tx = tid & 31, ty = tid >> 5;
  for (int r = ty; r < 32; r += 8) {
    const float v = keys[(size_t)(m0 + r) * D_ + d0 + tx];
    t[r][tx] = v;
    u16 h, l; split_f32(v, h, l);
    kh[(size_t)(m0 + r) * D_ + d0 + tx] = h;
    kl[(size_t)(m0 + r) * D_ + d0 + tx] = l;
  }
  __syncthreads();
  for (int r = ty; r < 32; r += 8) {
    const float v = t[tx][r];  // keys[m0+tx][d0+r]
    u16 h, l; split_f32(v, h, l);
    kth[(size_t)(d0 + r) * M_ + m0 + tx] = h;
    ktl[(size_t)(d0 + r) * M_ + m0 + tx] = l;
  }
}

// K1: l2-normalize over channel + transpose [B,C,N] -> [B,N,C] as bf16 hi/lo
__global__ __launch_bounds__(256) void k_norm_transpose(
    const float* __restrict__ q, u16* __restrict__ qf_hi,
    u16* __restrict__ qf_lo, float* __restrict__ inv_nrm) {
  __shared__ float tile[32][513];
  __shared__ float red[8][32];
  __shared__ float sinv[32];
  const int b = blockIdx.y;
  const int n0 = blockIdx.x * 32;
  const int tid = threadIdx.x;
  const int tx = tid & 31, ty = tid >> 5;
  const float* qb = q + (size_t)b * D_ * HW_ + n0;
  float ss = 0.f;
  for (int c = ty; c < D_; c += 8) {
    const float v = qb[(size_t)c * HW_ + tx];
    tile[tx][c] = v;
    ss += v * v;
  }
  red[ty][tx] = ss;
  __syncthreads();
  if (ty == 0) {
    float s = 0.f;
#pragma unroll
    for (int r = 0; r < 8; ++r) s += red[r][tx];
    const float inv = 1.0f / fmaxf(sqrtf(s), 1e-12f);
    sinv[tx] = inv;
    inv_nrm[b * N_ + n0 + tx] = inv;
  }
  __syncthreads();
  u16* qh = qf_hi + ((size_t)b * N_ + n0) * D_;
  u16* ql = qf_lo + ((size_t)b * N_ + n0) * D_;
  for (int i = tid; i < 32 * D_; i += 256) {
    const int nl = i >> 9, c = i & 511;
    const float x = tile[nl][c] * sinv[nl];
    u16 h, l; split_f32(x, h, l);
    qh[(size_t)nl * D_ + c] = h;
    ql[(size_t)nl * D_ + c] = l;
  }
}

// K2: score = qf . keys^T via 3-term bf16 MFMA (hi*hi + hi*lo + lo*hi)
__global__ __launch_bounds__(256, 2) void k_gemm_score_mfma(
    const u16* __restrict__ Ah_g, const u16* __restrict__ Al_g,
    const u16* __restrict__ Bh_g, const u16* __restrict__ Bl_g,
    float* __restrict__ score) {
  const int b = blockIdx.z;
  const int n0 = blockIdx.y * 128;
  const int m0 = blockIdx.x * 128;
  __shared__ __attribute__((aligned(16))) u16 sA[2][128][40];
  __shared__ __attribute__((aligned(16))) u16 sB[2][128][40];
  const int tid = threadIdx.x;
  const int lane = tid & 63;
  const int wave = tid >> 6;
  const int wr = wave >> 1, wc = wave & 1;
  const int frow = lane & 15;
  const int fk = (lane >> 4) << 3;
  const int r0 = tid >> 2, kc0 = (tid & 3) << 3;
  f4n acc[4][4] = {};
  const u16* Ag[2] = {Ah_g + (size_t)b * N_ * D_, Al_g + (size_t)b * N_ * D_};
  const u16* Bg[2] = {Bh_g, Bl_g};
  int4 ra[2][2], rb[2][2];
#pragma unroll
  for (int hl = 0; hl < 2; ++hl) {
    ra[hl][0] = *(const int4*)(Ag[hl] + (size_t)(n0 + r0) * D_ + kc0);
    ra[hl][1] = *(const int4*)(Ag[hl] + (size_t)(n0 + r0 + 64) * D_ + kc0);
    rb[hl][0] = *(const int4*)(Bg[hl] + (size_t)(m0 + r0) * D_ + kc0);
    rb[hl][1] = *(const int4*)(Bg[hl] + (size_t)(m0 + r0 + 64) * D_ + kc0);
  }
  for (int d0 = 0; d0 < 512; d0 += 32) {
    __syncthreads();
#pragma unroll
    for (int hl = 0; hl < 2; ++hl) {
      *(int4*)&sA[hl][r0][kc0] = ra[hl][0];
      *(int4*)&sA[hl][r0 + 64][kc0] = ra[hl][1];
      *(int4*)&sB[hl][r0][kc0] = rb[hl][0];
      *(int4*)&sB[hl][r0 + 64][kc0] = rb[hl][1];
    }
    __syncthreads();
    const int dn = (d0 + 32) & 511;
#pragma unroll
    for (int hl = 0; hl < 2; ++hl) {
      ra[hl][0] = *(const int4*)(Ag[hl] + (size_t)(n0 + r0) * D_ + dn + kc0);
      ra[hl][1] = *(const int4*)(Ag[hl] + (size_t)(n0 + r0 + 64) * D_ + dn + kc0);
      rb[hl][0] = *(const int4*)(Bg[hl] + (size_t)(m0 + r0) * D_ + dn + kc0);
      rb[hl][1] = *(const int4*)(Bg[hl] + (size_t)(m0 + r0 + 64) * D_ + dn + kc0);
    }
    bf8 af[2][4], bfr[2][4];
#pragma unroll
    for (int i = 0; i < 4; ++i) {
      af[0][i] = *(const bf8*)&sA[0][wr * 64 + i * 16 + frow][fk];
      af[1][i] = *(const bf8*)&sA[1][wr * 64 + i * 16 + frow][fk];
      bfr[0][i] = *(const bf8*)&sB[0][wc * 64 + i * 16 + frow][fk];
      bfr[1][i] = *(const bf8*)&sB[1][wc * 64 + i * 16 + frow][fk];
    }
#pragma unroll
    for (int i = 0; i < 4; ++i)
#pragma unroll
      for (int j = 0; j < 4; ++j) {
        acc[i][j] = __builtin_amdgcn_mfma_f32_16x16x32_bf16(af[0][i], bfr[0][j], acc[i][j], 0, 0, 0);
        acc[i][j] = __builtin_amdgcn_mfma_f32_16x16x32_bf16(af[0][i], bfr[1][j], acc[i][j], 0, 0, 0);
        acc[i][j] = __builtin_amdgcn_mfma_f32_16x16x32_bf16(af[1][i], bfr[0][j], acc[i][j], 0, 0, 0);
      }
  }
  float* Cb = score + ((size_t)b * N_ + n0 + wr * 64 + (lane >> 4) * 4) * M_ +
              m0 + wc * 64 + frow;
#pragma unroll
  for (int i = 0; i < 4; ++i)
#pragma unroll
    for (int j = 0; j < 4; ++j)
#pragma unroll
      for (int r = 0; r < 4; ++r)
        Cb[(size_t)(i * 16 + r) * M_ + j * 16] = acc[i][j][r];
}

// K3: colmax[b][m] = max_n score[b][n][m]  (before in-place softmax overwrite)
__global__ __launch_bounds__(256) void k_colmax(
    const float* __restrict__ score, float* __restrict__ colmax) {
  const int b = blockIdx.y, m0 = blockIdx.x * 32;
  const int tid = threadIdx.x, tx = tid & 31, ty = tid >> 5;
  const float* sb = score + (size_t)b * N_ * M_ + m0 + tx;
  float mx = -1e30f;
  for (int n = ty; n < N_; n += 8) mx = fmaxf(mx, sb[(size_t)n * M_]);
  __shared__ float red[8][33];
  red[ty][tx] = mx;
  __syncthreads();
  if (ty == 0) {
#pragma unroll
    for (int r = 1; r < 8; ++r) mx = fmaxf(mx, red[r][tx]);
    colmax[b * M_ + m0 + tx] = mx;
  }
}

// K4: per (b,n) row: top-2 + third-max, near-tie flagging, softmax over m
//     written in place as bf16 hi|lo, triplet losses, s_at, assign
__global__ __launch_bounds__(256) void k_softmax_top2(
    float* __restrict__ score, const u16* __restrict__ qf_hi,
    const u16* __restrict__ qf_lo, const float* __restrict__ keys,
    float* __restrict__ out2, float* __restrict__ out3,
    float* __restrict__ out4, float* __restrict__ s_at,
    int* __restrict__ assign, int* __restrict__ fix_cnt,
    int* __restrict__ fix_list) {
  const int bn = blockIdx.x;
  const int tid = threadIdx.x;
  float* row = score + (size_t)bn * M_;
  const float v0 = row[tid];
  const float v1 = row[tid + 256];
  float t1v, t2v; int t1i, t2i;
  if (v0 >= v1) { t1v = v0; t1i = tid;       t2v = v1; t2i = tid + 256; }
  else          { t1v = v1; t1i = tid + 256; t2v = v0; t2i = tid; }
  __shared__ float sv1[256], sv2[256];
  __shared__ int   si1[256], si2[256];
  sv1[tid] = t1v; si1[tid] = t1i; sv2[tid] = t2v; si2[tid] = t2i;
  __syncthreads();
  for (int s = 128; s > 0; s >>= 1) {
    if (tid < s) {
      const float a1 = sv1[tid];     const int a1i = si1[tid];
      const float a2 = sv2[tid];     const int a2i = si2[tid];
      const float b1 = sv1[tid + s]; const int b1i = si1[tid + s];
      const float b2 = sv2[tid + s]; const int b2i = si2[tid + s];
      if (b1 > a1 || (b1 == a1 && b1i < a1i)) {
        float n2; int n2i;
        if (a1 > b2 || (a1 == b2 && a1i < b2i)) { n2 = a1; n2i = a1i; }
        else                                    { n2 = b2; n2i = b2i; }
        sv1[tid] = b1; si1[tid] = b1i; sv2[tid] = n2; si2[tid] = n2i;
      } else {
        if (b1 > a2 || (b1 == a2 && b1i < a2i)) { sv2[tid] = b1; si2[tid] = b1i; }
      }
    }
    __syncthreads();
  }
  const float rowmax = sv1[0];
  const float second = sv2[0];
  const int i1 = si1[0];
  const int i2 = si2[0];
  __syncthreads();
  // third max (excluding i1, i2) -> near-tie flag
  float m3 = -1e30f;
  if (tid != i1 && tid != i2) m3 = v0;
  if (tid + 256 != i1 && tid + 256 != i2) m3 = fmaxf(m3, v1);
  sv1[tid] = m3;
  __syncthreads();
  for (int s = 128; s > 0; s >>= 1) {
    if (tid < s) sv1[tid] = fmaxf(sv1[tid], sv1[tid + s]);
    __syncthreads();
  }
  if (tid == 0) {
    const float third = sv1[0];
    if (rowmax - second < FIX_EPS || second - third < FIX_EPS) {
      const int p = atomicAdd(fix_cnt, 1);
      fix_list[p] = bn;
    }
  }
  __syncthreads();
  const float e0 = expf(v0 - rowmax), e1 = expf(v1 - rowmax);
  sv1[tid] = e0 + e1;
  __syncthreads();
  for (int s = 128; s > 0; s >>= 1) {
    if (tid < s) sv1[tid] += sv1[tid + s];
    __syncthreads();
  }
  const float invsum = 1.0f / sv1[0];
  // in-place bf16 hi|lo write of softmax probs (row fully read already)
  u16* rowU = (u16*)row;
  const float p0 = e0 * invsum, p1 = e1 * invsum;
  u16 h, l;
  split_f32(p0, h, l); rowU[tid] = h;       rowU[512 + tid] = l;
  split_f32(p1, h, l); rowU[tid + 256] = h; rowU[768 + tid] = l;
  __syncthreads();
  // losses (qf reconstructed from hi+lo)
  const u16* qh = qf_hi + (size_t)bn * D_;
  const u16* ql = qf_lo + (size_t)bn * D_;
  const float* pos = keys + (size_t)i1 * D_;
  const float* neg = keys + (size_t)i2 * D_;
  float* lc = out3 + (size_t)bn * D_;
  float dp = 0.f, dn = 0.f;
  for (int c = tid; c < D_; c += 256) {
    const float qv = bf2f(qh[c]) + bf2f(ql[c]);
    const float dP = qv - pos[c];
    lc[c] = dP * dP;
    const float a = dP + 1e-6f;
    dp += a * a;
    const float bb = (qv - neg[c]) + 1e-6f;
    dn += bb * bb;
  }
  sv1[tid] = dp; sv2[tid] = dn;
  __syncthreads();
  for (int s = 128; s > 0; s >>= 1) {
    if (tid < s) { sv1[tid] += sv1[tid + s]; sv2[tid] += sv2[tid + s]; }
    __syncthreads();
  }
  if (tid == 0) {
    out2[bn] = fmaxf(sqrtf(sv1[0]) - sqrtf(sv2[0]) + 1.0f, 0.0f);
    out4[bn] = (float)i1;
    s_at[bn] = rowmax;
    assign[bn] = i1;
  }
}

// K4b: exact fp32 re-score for flagged near-tie rows; rewrites losses/indices
__global__ __launch_bounds__(256) void k_fixup(
    const int* __restrict__ fix_cnt, const int* __restrict__ fix_list,
    const float* __restrict__ q, const float* __restrict__ inv_nrm,
    const float* __restrict__ keys, float* __restrict__ out2,
    float* __restrict__ out3, float* __restrict__ out4,
    float* __restrict__ s_at, int* __restrict__ assign) {
  const int cnt = *fix_cnt;
  const int tid = threadIdx.x;
  __shared__ float qrow[512];
  __shared__ float sv1[256], sv2[256];
  __shared__ int   si1[256], si2[256];
  for (int idx = blockIdx.x; idx < cnt; idx += gridDim.x) {
    const int bn = fix_list[idx];
    const int b = bn >> 12;
    const int n = bn & 4095;
    const float inv = inv_nrm[bn];
    for (int c = tid; c < 512; c += 256)
      qrow[c] = q[((size_t)b * D_ + c) * (size_t)HW_ + n] * inv;
    __syncthreads();
    // exact fp32 scores for m = tid and m = tid+256
    float sc0 = 0.f, sc1 = 0.f;
    const float* k0 = keys + (size_t)tid * D_;
    const float* k1 = keys + (size_t)(tid + 256) * D_;
    for (int d = 0; d < 512; ++d) {
      const float qv = qrow[d];
      sc0 = fmaf(qv, k0[d], sc0);
      sc1 = fmaf(qv, k1[d], sc1);
    }
    float t1v, t2v; int t1i, t2i;
    if (sc0 >= sc1) { t1v = sc0; t1i = tid;       t2v = sc1; t2i = tid + 256; }
    else            { t1v = sc1; t1i = tid + 256; t2v = sc0; t2i = tid; }
    sv1[tid] = t1v; si1[tid] = t1i; sv2[tid] = t2v; si2[tid] = t2i;
    __syncthreads();
    for (int s = 128; s > 0; s >>= 1) {
      if (tid < s) {
        const float a1 = sv1[tid];     const int a1i = si1[tid];
        const float a2 = sv2[tid];     const int a2i = si2[tid];
        const float b1 = sv1[tid + s]; const int b1i = si1[tid + s];
        const float b2 = sv2[tid + s]; const int b2i = si2[tid + s];
        if (b1 > a1 || (b1 == a1 && b1i < a1i)) {
          float n2; int n2i;
          if (a1 > b2 || (a1 == b2 && a1i < b2i)) { n2 = a1; n2i = a1i; }
          else                                    { n2 = b2; n2i = b2i; }
          sv1[tid] = b1; si1[tid] = b1i; sv2[tid] = n2; si2[tid] = n2i;
        } else {
          if (b1 > a2 || (b1 == a2 && b1i < a2i)) { sv2[tid] = b1; si2[tid] = b1i; }
        }
      }
      __syncthreads();
    }
    const float rowmax = sv1[0];
    const int i1 = si1[0];
    const int i2 = si2[0];
    __syncthreads();
    // exact losses
    const float* pos = keys + (size_t)i1 * D_;
    const float* neg = keys + (size_t)i2 * D_;
    float* lc = out3 + (size_t)bn * D_;
    float dp = 0.f, dn = 0.f;
    for (int c = tid; c < D_; c += 256) {
      const float qv = qrow[c];
      const float dP = qv - pos[c];
      lc[c] = dP * dP;
      const float a = dP + 1e-6f;
      dp += a * a;
      const float bb = (qv - neg[c]) + 1e-6f;
      dn += bb * bb;
    }
    sv1[tid] = dp; sv2[tid] = dn;
    __syncthreads();
    for (int s = 128; s > 0; s >>= 1) {
      if (tid < s) { sv1[tid] += sv1[tid + s]; sv2[tid] += sv2[tid + s]; }
      __syncthreads();
    }
    if (tid == 0) {
      out2[bn] = fmaxf(sqrtf(sv1[0]) - sqrtf(sv2[0]) + 1.0f, 0.0f);
      out4[bn] = (float)i1;
      s_at[bn] = rowmax;
      assign[bn] = i1;
    }
    __syncthreads();
  }
}

// K5: qu[b][m][:] = sum_{n: assign=m} exp(s_at[b,n]-colmax[b,m]) * qf[b][n][:]
__global__ __launch_bounds__(256) void k_update_gather(
    const int* __restrict__ assign, const float* __restrict__ s_at,
    const float* __restrict__ colmax, const u16* __restrict__ qf_hi,
    const u16* __restrict__ qf_lo, float* __restrict__ qu) {
  const int m = blockIdx.x;
  const int b = blockIdx.y;
  __shared__ int list[4096];
  __shared__ int cnt;
  const int tid = threadIdx.x;
  if (tid == 0) cnt = 0;
  __syncthreads();
  const int* ab = assign + b * N_;
  for (int n = tid; n < N_; n += 256) {
    if (ab[n] == m) { const int p = atomicAdd(&cnt, 1); list[p] = n; }
  }
  __syncthreads();
  const float cm = colmax[b * M_ + m];
  const int c0 = tid, c1 = tid + 256;
  float acc0 = 0.f, acc1 = 0.f;
  const int K = cnt;
  for (int i = 0; i < K; ++i) {
    const int n = list[i];
    const float w = expf(s_at[b * N_ + n] - cm);
    const u16* qh = qf_hi + ((size_t)b * N_ + n) * D_;
    const u16* ql = qf_lo + ((size_t)b * N_ + n) * D_;
    acc0 += w * (bf2f(qh[c0]) + bf2f(ql[c0]));
    acc1 += w * (bf2f(qh[c1]) + bf2f(ql[c1]));
  }
  float* orow = qu + ((size_t)b * M_ + m) * D_;
  orow[c0] = acc0;
  orow[c1] = acc1;
}

// K6: fused 8-step scan (rows independent): mem = l2norm(mem + qu_b), b=0..7
__global__ __launch_bounds__(256) void k_mem_fused(
    const float* __restrict__ keys, const float* __restrict__ qu,
    float* __restrict__ out1) {
  const int m = blockIdx.x, tid = threadIdx.x;
  const size_t base = (size_t)m * D_;
  float v0 = keys[base + tid], v1 = keys[base + tid + 256];
  __shared__ float red[256];
  for (int b = 0; b < B_; ++b) {
    const float* qb = qu + (size_t)b * M_ * D_ + base;
    v0 += qb[tid]; v1 += qb[tid + 256];
    red[tid] = v0 * v0 + v1 * v1;
    __syncthreads();
    for (int s = 128; s > 0; s >>= 1) {
      if (tid < s) red[tid] += red[tid + s];
      __syncthreads();
    }
    const float inv = 1.0f / fmaxf(sqrtf(red[0]), 1e-12f);
    v0 *= inv; v1 *= inv;
    __syncthreads();
  }
  out1[base + tid] = v0;
  out1[base + tid + 256] = v1;
}

// K7a: updated_query[:, :512, :, :] = q * inv_norm (elementwise, orig layout)
__global__ __launch_bounds__(256) void k_out_first(
    const float* __restrict__ q, const float* __restrict__ inv_nrm,
    float* __restrict__ out0) {
  const size_t i4 = (size_t)blockIdx.x * 256 + threadIdx.x;
  const size_t base = i4 * 4;
  const int n = (int)(base & 4095);
  const size_t bc = base >> 12;
  const size_t b = bc >> 9;
  const float4 v = *(const float4*)(q + base);
  const float4 w = *(const float4*)(inv_nrm + b * N_ + n);
  *(float4*)(out0 + ((bc + b * 512) << 12) + n) =
      make_float4(v.x * w.x, v.y * w.y, v.z * w.z, v.w * w.w);
}

// K7b: out0[b][512+d][n] = sum_m sm[b][n][m]*keysT[d][m], 3-term bf16 MFMA.
__global__ __launch_bounds__(256, 2) void k_gemm_concat_mfma(
    const u16* __restrict__ smU, const u16* __restrict__ Bh_g,
    const u16* __restrict__ Bl_g, float* __restrict__ out0) {
  const int b = blockIdx.z;
  const int n0 = blockIdx.y * 128;
  const int d0b = blockIdx.x * 128;
  __shared__ __attribute__((aligned(16))) u16 sA[2][128][40];
  __shared__ __attribute__((aligned(16))) u16 sB[2][128][40];
  const int tid = threadIdx.x;
  const int lane = tid & 63;
  const int wave = tid >> 6;
  const int wr = wave >> 1, wc = wave & 1;
  const int frow = lane & 15;
  const int fk = (lane >> 4) << 3;
  const int r0 = tid >> 2, kc0 = (tid & 3) << 3;
  f4n acc[4][4] = {};
  const u16* Ab = smU + (size_t)b * N_ * 1024;
  const u16* Bg[2] = {Bh_g, Bl_g};
  int4 ra[2][2], rb[2][2];
#pragma unroll
  for (int hl = 0; hl < 2; ++hl) {
    const int off = hl * 512;
    ra[hl][0] = *(const int4*)(Ab + (size_t)(n0 + r0) * 1024 + off + kc0);
    ra[hl][1] = *(const int4*)(Ab + (size_t)(n0 + r0 + 64) * 1024 + off + kc0);
    rb[hl][0] = *(const int4*)(Bg[hl] + (size_t)(d0b + r0) * M_ + kc0);
    rb[hl][1] = *(const int4*)(Bg[hl] + (size_t)(d0b + r0 + 64) * M_ + kc0);
  }
  for (int k0 = 0; k0 < 512; k0 += 32) {
    __syncthreads();
#pragma unroll
    for (int hl = 0; hl < 2; ++hl) {
      *(int4*)&sA[hl][r0][kc0] = ra[hl][0];
      *(int4*)&sA[hl][r0 + 64][kc0] = ra[hl][1];
      *(int4*)&sB[hl][r0][kc0] = rb[hl][0];
      *(int4*)&sB[hl][r0 + 64][kc0] = rb[hl][1];
    }
    __syncthreads();
    const int kn = (k0 + 32) & 511;
#pragma unroll
    for (int hl = 0; hl < 2; ++hl) {
      const int off = hl * 512;
      ra[hl][0] = *(const int4*)(Ab + (size_t)(n0 + r0) * 1024 + off + kn + kc0);
      ra[hl][1] = *(const int4*)(Ab + (size_t)(n0 + r0 + 64) * 1024 + off + kn + kc0);
      rb[hl][0] = *(const int4*)(Bg[hl] + (size_t)(d0b + r0) * M_ + kn + kc0);
      rb[hl][1] = *(const int4*)(Bg[hl] + (size_t)(d0b + r0 + 64) * M_ + kn + kc0);
    }
    bf8 af[2][4], bfr[2][4];
#pragma unroll
    for (int i = 0; i < 4; ++i) {
      af[0][i] = *(const bf8*)&sA[0][wr * 64 + i * 16 + frow][fk];
      af[1][i] = *(const bf8*)&sA[1][wr * 64 + i * 16 + frow][fk];
      bfr[0][i] = *(const bf8*)&sB[0][wc * 64 + i * 16 + frow][fk];
      bfr[1][i] = *(const bf8*)&sB[1][wc * 64 + i * 16 + frow][fk];
    }
#pragma unroll
    for (int i = 0; i < 4; ++i)
#pragma unroll
      for (int j = 0; j < 4; ++j) {
        acc[i][j] = __builtin_amdgcn_mfma_f32_16x16x32_bf16(af[0][i], bfr[0][j], acc[i][j], 0, 0, 0);
        acc[i][j] = __builtin_amdgcn_mfma_f32_16x16x32_bf16(af[0][i], bfr[1][j], acc[i][j], 0, 0, 0);
        acc[i][j] = __builtin_amdgcn_mfma_f32_16x16x32_bf16(af[1][i], bfr[0][j], acc[i][j], 0, 0, 0);
      }
  }
  float* outb = out0 + ((size_t)b * 1024 + 512) * (size_t)HW_;
#pragma unroll
  for (int i = 0; i < 4; ++i) {
    const int nr = n0 + wr * 64 + i * 16 + ((lane >> 4) << 2);
#pragma unroll
    for (int j = 0; j < 4; ++j) {
      const int dcol = d0b + wc * 64 + j * 16 + frow;
      *(f4n*)(outb + (size_t)dcol * HW_ + nr) = acc[i][j];
    }
  }
}

extern "C" void kernel_launch(void* const* d_in, const int* in_sizes, int n_in,
                              void* d_out, int out_size, void* d_ws, size_t ws_size,
                              hipStream_t stream) {
  const float* q = (const float*)d_in[0];     // [8,512,64,64]
  const float* keys = (const float*)d_in[1];  // [512,512]
  float* out = (float*)d_out;
  float* ws = (float*)d_ws;

  float* score    = ws;
  u16*   qf_hi    = (u16*)(ws + 16777216);
  u16*   qf_lo    = (u16*)(ws + 25165824);
  float* qu       = ws + 33554432;
  float* inv_nrm  = ws + 35651584;
  float* s_at     = ws + 35684352;
  float* colmax   = ws + 35717120;
  int*   assign   = (int*)(ws + 35721216);
  u16*   keys_hi  = (u16*)(ws + 35753984);
  u16*   keys_lo  = (u16*)(ws + 35885056);
  u16*   keysT_hi = (u16*)(ws + 36016128);
  u16*   keysT_lo = (u16*)(ws + 36147200);
  int*   fix_cnt  = (int*)(ws + 36278272);
  int*   fix_list = (int*)(ws + 36278273);

  float* out0 = out;             // updated_query  [8,1024,64,64]
  float* out1 = out + 33554432;  // updated_memory [512,512]
  float* out2 = out + 33816576;  // loss_separate  [8,4096]
  float* out3 = out + 33849344;  // loss_compact   [8,4096,512]
  float* out4 = out + 50626560;  // closest idx    [8,4096]

  k_split_keys<<<dim3(16, 16), 256, 0, stream>>>(keys, keys_hi, keys_lo,
                                                 keysT_hi, keysT_lo, fix_cnt);
  k_norm_transpose<<<dim3(N_ / 32, B_), 256, 0, stream>>>(q, qf_hi, qf_lo, inv_nrm);
  k_gemm_score_mfma<<<dim3(M_ / 128, N_ / 128, B_), 256, 0, stream>>>(
      qf_hi, qf_lo, keys_hi, keys_lo, score);
  k_colmax<<<dim3(M_ / 32, B_), 256, 0, stream>>>(score, colmax);
  k_softmax_top2<<<dim3(B_ * N_), 256, 0, stream>>>(score, qf_hi, qf_lo, keys,
                                                    out2, out3, out4, s_at,
                                                    assign, fix_cnt, fix_list);
  k_fixup<<<dim3(256), 256, 0, stream>>>(fix_cnt, fix_list, q, inv_nrm, keys,
                                         out2, out3, out4, s_at, assign);
  k_update_gather<<<dim3(M_, B_), 256, 0, stream>>>(assign, s_at, colmax,
                                                    qf_hi, qf_lo, qu);
  k_mem_fused<<<dim3(M_), 256, 0, stream>>>(keys, qu, out1);
  k_out_first<<<dim3((B_ * D_ * HW_ / 4) / 256), 256, 0, stream>>>(q, inv_nrm, out0);
  k_gemm_concat_mfma<<<dim3(D_ / 128, N_ / 128, B_), 256, 0, stream>>>(
      (const u16*)score, keysT_hi, keysT_lo, out0);
}

// Round 4
// 1120.670 us; speedup vs baseline: 1.0054x; 1.0054x over previous
//
#include <hip/hip_runtime.h>
#include <cstdint>
#include <cstddef>

#define B_  8
#define N_  4096   // H*W
#define M_  512    // memory slots
#define D_  512    // feature dim (= C)
#define HW_ 4096

#define FIX_EPS 4e-3f

typedef unsigned short u16;
typedef unsigned int   u32;
typedef short bf8 __attribute__((ext_vector_type(8)));
typedef float f4n __attribute__((ext_vector_type(4)));

__device__ __forceinline__ float bf2f(u16 u) {
  return __uint_as_float(((u32)u) << 16);
}
__device__ __forceinline__ void split_f32(float x, u16& hi, u16& lo) {
  const u32 xb = __float_as_uint(x);
  hi = (u16)(xb >> 16);
  const float hif = __uint_as_float(xb & 0xffff0000u);
  lo = (u16)(__float_as_uint(x - hif) >> 16);
}

// LDS tile addressing: row-major [row][BK=32 u16], XOR chunk swizzle so that
// fragment reads (16 rows x 4 16B-chunks) and staging writes hit the inherent
// 8-words/bank minimum with only 2-way start aliasing (free on CDNA4).
__device__ __forceinline__ int lds_off(int row, int chunk) {
  return row * 32 + ((chunk ^ ((row >> 1) & 3)) << 3);
}

// -------- workspace layout (float offsets) --------
// score   : 0          [B,N,M] fp32 (raw; then in-place bf16 hi|lo softmax)
// qf_hi   : 16777216   [B,N,D] u16   qf_lo: 25165824
// qu      : 33554432   [B,M,D] fp32
// inv_nrm : 35651584   [B,N]
// s_at    : 35684352   [B,N]
// colmax  : 35717120   [B,M]
// assign  : 35721216   [B,N] int
// keys_hi : 35753984   keys_lo: 35885056   keysT_hi: 36016128  keysT_lo: 36147200
// fix_cnt : 36278272   (1 int)
// fix_list: 36278273   (32768 int)

// K0: split keys into bf16 hi/lo (+ transposed copies); zero fixup counter
__global__ __launch_bounds__(256) void k_split_keys(
    const float* __restrict__ keys, u16* __restrict__ kh, u16* __restrict__ kl,
    u16* __restrict__ kth, u16* __restrict__ ktl, int* __restrict__ fix_cnt) {
  if (blockIdx.x == 0 && blockIdx.y == 0 && threadIdx.x == 0) *fix_cnt = 0;
  __shared__ float t[32][33];
  const int d0 = blockIdx.x * 32, m0 = blockIdx.y * 32;
  const int tid = threadIdx.x, tx = tid & 31, ty = tid >> 5;
  for (int r = ty; r < 32; r += 8) {
    const float v = keys[(size_t)(m0 + r) * D_ + d0 + tx];
    t[r][tx] = v;
    u16 h, l; split_f32(v, h, l);
    kh[(size_t)(m0 + r) * D_ + d0 + tx] = h;
    kl[(size_t)(m0 + r) * D_ + d0 + tx] = l;
  }
  __syncthreads();
  for (int r = ty; r < 32; r += 8) {
    const float v = t[tx][r];  // keys[m0+tx][d0+r]
    u16 h, l; split_f32(v, h, l);
    kth[(size_t)(d0 + r) * M_ + m0 + tx] = h;
    ktl[(size_t)(d0 + r) * M_ + m0 + tx] = l;
  }
}

// K1: l2-normalize over channel + transpose [B,C,N] -> [B,N,C] as bf16 hi/lo
__global__ __launch_bounds__(256) void k_norm_transpose(
    const float* __restrict__ q, u16* __restrict__ qf_hi,
    u16* __restrict__ qf_lo, float* __restrict__ inv_nrm) {
  __shared__ float tile[32][513];
  __shared__ float red[8][32];
  __shared__ float sinv[32];
  const int b = blockIdx.y;
  const int n0 = blockIdx.x * 32;
  const int tid = threadIdx.x;
  const int tx = tid & 31, ty = tid >> 5;
  const float* qb = q + (size_t)b * D_ * HW_ + n0;
  float ss = 0.f;
  for (int c = ty; c < D_; c += 8) {
    const float v = qb[(size_t)c * HW_ + tx];
    tile[tx][c] = v;
    ss += v * v;
  }
  red[ty][tx] = ss;
  __syncthreads();
  if (ty == 0) {
    float s = 0.f;
#pragma unroll
    for (int r = 0; r < 8; ++r) s += red[r][tx];
    const float inv = 1.0f / fmaxf(sqrtf(s), 1e-12f);
    sinv[tx] = inv;
    inv_nrm[b * N_ + n0 + tx] = inv;
  }
  __syncthreads();
  u16* qh = qf_hi + ((size_t)b * N_ + n0) * D_;
  u16* ql = qf_lo + ((size_t)b * N_ + n0) * D_;
  for (int i = tid; i < 32 * D_; i += 256) {
    const int nl = i >> 9, c = i & 511;
    const float x = tile[nl][c] * sinv[nl];
    u16 h, l; split_f32(x, h, l);
    qh[(size_t)nl * D_ + c] = h;
    ql[(size_t)nl * D_ + c] = l;
  }
}

// K2: score = qf . keys^T via 3-term bf16 MFMA (hi*hi + hi*lo + lo*hi).
// LDS: A/B tiles swizzled; epilogue stages C in LDS, writes 512B-contiguous.
__global__ __launch_bounds__(256, 2) void k_gemm_score_mfma(
    const u16* __restrict__ Ah_g, const u16* __restrict__ Al_g,
    const u16* __restrict__ Bh_g, const u16* __restrict__ Bl_g,
    float* __restrict__ score) {
  const int b = blockIdx.z;
  const int n0 = blockIdx.y * 128;
  const int m0 = blockIdx.x * 128;
  __shared__ __attribute__((aligned(16))) char smem[33792];
  u16* sA = (u16*)smem;          // [2][128][32]
  u16* sB = (u16*)smem + 8192;   // [2][128][32]
  float* stage = (float*)smem;   // [64][132] (reused after main loop)
  const int tid = threadIdx.x;
  const int lane = tid & 63;
  const int wave = tid >> 6;
  const int wr = wave >> 1, wc = wave & 1;
  const int frow = lane & 15;
  const int fchunk = lane >> 4;                       // 16B chunk of BK
  const int rchunk = fchunk ^ ((frow >> 1) & 3);      // swizzled
  const int r0 = tid >> 2, c0 = tid & 3, kc0 = c0 << 3;
  const int woff0 = lds_off(r0, c0);
  const int woff1 = lds_off(r0 + 64, c0);
  f4n acc[4][4] = {};
  const u16* Ag[2] = {Ah_g + (size_t)b * N_ * D_, Al_g + (size_t)b * N_ * D_};
  const u16* Bg[2] = {Bh_g, Bl_g};
  int4 ra[2][2], rb[2][2];
#pragma unroll
  for (int hl = 0; hl < 2; ++hl) {
    ra[hl][0] = *(const int4*)(Ag[hl] + (size_t)(n0 + r0) * D_ + kc0);
    ra[hl][1] = *(const int4*)(Ag[hl] + (size_t)(n0 + r0 + 64) * D_ + kc0);
    rb[hl][0] = *(const int4*)(Bg[hl] + (size_t)(m0 + r0) * D_ + kc0);
    rb[hl][1] = *(const int4*)(Bg[hl] + (size_t)(m0 + r0 + 64) * D_ + kc0);
  }
  for (int d0 = 0; d0 < 512; d0 += 32) {
    __syncthreads();
#pragma unroll
    for (int hl = 0; hl < 2; ++hl) {
      *(int4*)(sA + hl * 4096 + woff0) = ra[hl][0];
      *(int4*)(sA + hl * 4096 + woff1) = ra[hl][1];
      *(int4*)(sB + hl * 4096 + woff0) = rb[hl][0];
      *(int4*)(sB + hl * 4096 + woff1) = rb[hl][1];
    }
    __syncthreads();
    const int dn = (d0 + 32) & 511;
#pragma unroll
    for (int hl = 0; hl < 2; ++hl) {
      ra[hl][0] = *(const int4*)(Ag[hl] + (size_t)(n0 + r0) * D_ + dn + kc0);
      ra[hl][1] = *(const int4*)(Ag[hl] + (size_t)(n0 + r0 + 64) * D_ + dn + kc0);
      rb[hl][0] = *(const int4*)(Bg[hl] + (size_t)(m0 + r0) * D_ + dn + kc0);
      rb[hl][1] = *(const int4*)(Bg[hl] + (size_t)(m0 + r0 + 64) * D_ + dn + kc0);
    }
    bf8 af[2][4], bfr[2][4];
#pragma unroll
    for (int i = 0; i < 4; ++i) {
      const int arow = wr * 64 + i * 16 + frow;
      const int brow = wc * 64 + i * 16 + frow;
      const int koff = rchunk << 3;
      af[0][i] = *(const bf8*)(sA + arow * 32 + koff);
      af[1][i] = *(const bf8*)(sA + 4096 + arow * 32 + koff);
      bfr[0][i] = *(const bf8*)(sB + brow * 32 + koff);
      bfr[1][i] = *(const bf8*)(sB + 4096 + brow * 32 + koff);
    }
#pragma unroll
    for (int i = 0; i < 4; ++i)
#pragma unroll
      for (int j = 0; j < 4; ++j) {
        acc[i][j] = __builtin_amdgcn_mfma_f32_16x16x32_bf16(af[0][i], bfr[0][j], acc[i][j], 0, 0, 0);
        acc[i][j] = __builtin_amdgcn_mfma_f32_16x16x32_bf16(af[0][i], bfr[1][j], acc[i][j], 0, 0, 0);
        acc[i][j] = __builtin_amdgcn_mfma_f32_16x16x32_bf16(af[1][i], bfr[0][j], acc[i][j], 0, 0, 0);
      }
  }
  // Epilogue: per n-half, stage 64x128 C in LDS then write 512B-contiguous.
  const int q4 = (lane >> 4) << 2;
#pragma unroll
  for (int h = 0; h < 2; ++h) {
    __syncthreads();
    if (wr == h) {
#pragma unroll
      for (int i = 0; i < 4; ++i)
#pragma unroll
        for (int j = 0; j < 4; ++j)
#pragma unroll
          for (int r = 0; r < 4; ++r)
            stage[(i * 16 + q4 + r) * 132 + wc * 64 + j * 16 + frow] = acc[i][j][r];
    }
    __syncthreads();
    float* Crow = score + ((size_t)b * N_ + n0 + 64 * h) * M_ + m0;
    const int cc = (tid & 31) << 2;
#pragma unroll
    for (int p = 0; p < 8; ++p) {
      const int row = p * 8 + (tid >> 5);
      *(f4n*)(Crow + (size_t)row * M_ + cc) = *(const f4n*)&stage[row * 132 + cc];
    }
  }
}

// K3: colmax[b][m] = max_n score[b][n][m]  (before in-place softmax overwrite)
__global__ __launch_bounds__(256) void k_colmax(
    const float* __restrict__ score, float* __restrict__ colmax) {
  const int b = blockIdx.y, m0 = blockIdx.x * 32;
  const int tid = threadIdx.x, tx = tid & 31, ty = tid >> 5;
  const float* sb = score + (size_t)b * N_ * M_ + m0 + tx;
  float mx = -1e30f;
  for (int n = ty; n < N_; n += 8) mx = fmaxf(mx, sb[(size_t)n * M_]);
  __shared__ float red[8][33];
  red[ty][tx] = mx;
  __syncthreads();
  if (ty == 0) {
#pragma unroll
    for (int r = 1; r < 8; ++r) mx = fmaxf(mx, red[r][tx]);
    colmax[b * M_ + m0 + tx] = mx;
  }
}

// K4: per (b,n) row: top-2 + third-max, near-tie flagging, softmax over m
//     written in place as bf16 hi|lo, triplet losses, s_at, assign
__global__ __launch_bounds__(256) void k_softmax_top2(
    float* __restrict__ score, const u16* __restrict__ qf_hi,
    const u16* __restrict__ qf_lo, const float* __restrict__ keys,
    float* __restrict__ out2, float* __restrict__ out3,
    float* __restrict__ out4, float* __restrict__ s_at,
    int* __restrict__ assign, int* __restrict__ fix_cnt,
    int* __restrict__ fix_list) {
  const int bn = blockIdx.x;
  const int tid = threadIdx.x;
  float* row = score + (size_t)bn * M_;
  const float v0 = row[tid];
  const float v1 = row[tid + 256];
  float t1v, t2v; int t1i, t2i;
  if (v0 >= v1) { t1v = v0; t1i = tid;       t2v = v1; t2i = tid + 256; }
  else          { t1v = v1; t1i = tid + 256; t2v = v0; t2i = tid; }
  __shared__ float sv1[256], sv2[256];
  __shared__ int   si1[256], si2[256];
  sv1[tid] = t1v; si1[tid] = t1i; sv2[tid] = t2v; si2[tid] = t2i;
  __syncthreads();
  for (int s = 128; s > 0; s >>= 1) {
    if (tid < s) {
      const float a1 = sv1[tid];     const int a1i = si1[tid];
      const float a2 = sv2[tid];     const int a2i = si2[tid];
      const float b1 = sv1[tid + s]; const int b1i = si1[tid + s];
      const float b2 = sv2[tid + s]; const int b2i = si2[tid + s];
      if (b1 > a1 || (b1 == a1 && b1i < a1i)) {
        float n2; int n2i;
        if (a1 > b2 || (a1 == b2 && a1i < b2i)) { n2 = a1; n2i = a1i; }
        else                                    { n2 = b2; n2i = b2i; }
        sv1[tid] = b1; si1[tid] = b1i; sv2[tid] = n2; si2[tid] = n2i;
      } else {
        if (b1 > a2 || (b1 == a2 && b1i < a2i)) { sv2[tid] = b1; si2[tid] = b1i; }
      }
    }
    __syncthreads();
  }
  const float rowmax = sv1[0];
  const float second = sv2[0];
  const int i1 = si1[0];
  const int i2 = si2[0];
  __syncthreads();
  // third max (excluding i1, i2) -> near-tie flag
  float m3 = -1e30f;
  if (tid != i1 && tid != i2) m3 = v0;
  if (tid + 256 != i1 && tid + 256 != i2) m3 = fmaxf(m3, v1);
  sv1[tid] = m3;
  __syncthreads();
  for (int s = 128; s > 0; s >>= 1) {
    if (tid < s) sv1[tid] = fmaxf(sv1[tid], sv1[tid + s]);
    __syncthreads();
  }
  if (tid == 0) {
    const float third = sv1[0];
    if (rowmax - second < FIX_EPS || second - third < FIX_EPS) {
      const int p = atomicAdd(fix_cnt, 1);
      fix_list[p] = bn;
    }
  }
  __syncthreads();
  const float e0 = expf(v0 - rowmax), e1 = expf(v1 - rowmax);
  sv1[tid] = e0 + e1;
  __syncthreads();
  for (int s = 128; s > 0; s >>= 1) {
    if (tid < s) sv1[tid] += sv1[tid + s];
    __syncthreads();
  }
  const float invsum = 1.0f / sv1[0];
  // in-place bf16 hi|lo write of softmax probs (row fully read already)
  u16* rowU = (u16*)row;
  const float p0 = e0 * invsum, p1 = e1 * invsum;
  u16 h, l;
  split_f32(p0, h, l); rowU[tid] = h;       rowU[512 + tid] = l;
  split_f32(p1, h, l); rowU[tid + 256] = h; rowU[768 + tid] = l;
  __syncthreads();
  // losses (qf reconstructed from hi+lo)
  const u16* qh = qf_hi + (size_t)bn * D_;
  const u16* ql = qf_lo + (size_t)bn * D_;
  const float* pos = keys + (size_t)i1 * D_;
  const float* neg = keys + (size_t)i2 * D_;
  float* lc = out3 + (size_t)bn * D_;
  float dp = 0.f, dn = 0.f;
  for (int c = tid; c < D_; c += 256) {
    const float qv = bf2f(qh[c]) + bf2f(ql[c]);
    const float dP = qv - pos[c];
    lc[c] = dP * dP;
    const float a = dP + 1e-6f;
    dp += a * a;
    const float bb = (qv - neg[c]) + 1e-6f;
    dn += bb * bb;
  }
  sv1[tid] = dp; sv2[tid] = dn;
  __syncthreads();
  for (int s = 128; s > 0; s >>= 1) {
    if (tid < s) { sv1[tid] += sv1[tid + s]; sv2[tid] += sv2[tid + s]; }
    __syncthreads();
  }
  if (tid == 0) {
    out2[bn] = fmaxf(sqrtf(sv1[0]) - sqrtf(sv2[0]) + 1.0f, 0.0f);
    out4[bn] = (float)i1;
    s_at[bn] = rowmax;
    assign[bn] = i1;
  }
}

// K4b: exact fp32 re-score for flagged near-tie rows; rewrites losses/indices
__global__ __launch_bounds__(256) void k_fixup(
    const int* __restrict__ fix_cnt, const int* __restrict__ fix_list,
    const float* __restrict__ q, const float* __restrict__ inv_nrm,
    const float* __restrict__ keys, float* __restrict__ out2,
    float* __restrict__ out3, float* __restrict__ out4,
    float* __restrict__ s_at, int* __restrict__ assign) {
  const int cnt = *fix_cnt;
  const int tid = threadIdx.x;
  __shared__ float qrow[512];
  __shared__ float sv1[256], sv2[256];
  __shared__ int   si1[256], si2[256];
  for (int idx = blockIdx.x; idx < cnt; idx += gridDim.x) {
    const int bn = fix_list[idx];
    const int b = bn >> 12;
    const int n = bn & 4095;
    const float inv = inv_nrm[bn];
    for (int c = tid; c < 512; c += 256)
      qrow[c] = q[((size_t)b * D_ + c) * (size_t)HW_ + n] * inv;
    __syncthreads();
    float sc0 = 0.f, sc1 = 0.f;
    const float* k0 = keys + (size_t)tid * D_;
    const float* k1 = keys + (size_t)(tid + 256) * D_;
    for (int d = 0; d < 512; ++d) {
      const float qv = qrow[d];
      sc0 = fmaf(qv, k0[d], sc0);
      sc1 = fmaf(qv, k1[d], sc1);
    }
    float t1v, t2v; int t1i, t2i;
    if (sc0 >= sc1) { t1v = sc0; t1i = tid;       t2v = sc1; t2i = tid + 256; }
    else            { t1v = sc1; t1i = tid + 256; t2v = sc0; t2i = tid; }
    sv1[tid] = t1v; si1[tid] = t1i; sv2[tid] = t2v; si2[tid] = t2i;
    __syncthreads();
    for (int s = 128; s > 0; s >>= 1) {
      if (tid < s) {
        const float a1 = sv1[tid];     const int a1i = si1[tid];
        const float a2 = sv2[tid];     const int a2i = si2[tid];
        const float b1 = sv1[tid + s]; const int b1i = si1[tid + s];
        const float b2 = sv2[tid + s]; const int b2i = si2[tid + s];
        if (b1 > a1 || (b1 == a1 && b1i < a1i)) {
          float n2; int n2i;
          if (a1 > b2 || (a1 == b2 && a1i < b2i)) { n2 = a1; n2i = a1i; }
          else                                    { n2 = b2; n2i = b2i; }
          sv1[tid] = b1; si1[tid] = b1i; sv2[tid] = n2; si2[tid] = n2i;
        } else {
          if (b1 > a2 || (b1 == a2 && b1i < a2i)) { sv2[tid] = b1; si2[tid] = b1i; }
        }
      }
      __syncthreads();
    }
    const float rowmax = sv1[0];
    const int i1 = si1[0];
    const int i2 = si2[0];
    __syncthreads();
    const float* pos = keys + (size_t)i1 * D_;
    const float* neg = keys + (size_t)i2 * D_;
    float* lc = out3 + (size_t)bn * D_;
    float dp = 0.f, dn = 0.f;
    for (int c = tid; c < D_; c += 256) {
      const float qv = qrow[c];
      const float dP = qv - pos[c];
      lc[c] = dP * dP;
      const float a = dP + 1e-6f;
      dp += a * a;
      const float bb = (qv - neg[c]) + 1e-6f;
      dn += bb * bb;
    }
    sv1[tid] = dp; sv2[tid] = dn;
    __syncthreads();
    for (int s = 128; s > 0; s >>= 1) {
      if (tid < s) { sv1[tid] += sv1[tid + s]; sv2[tid] += sv2[tid + s]; }
      __syncthreads();
    }
    if (tid == 0) {
      out2[bn] = fmaxf(sqrtf(sv1[0]) - sqrtf(sv2[0]) + 1.0f, 0.0f);
      out4[bn] = (float)i1;
      s_at[bn] = rowmax;
      assign[bn] = i1;
    }
    __syncthreads();
  }
}

// K5: qu[b][m][:] = sum_{n: assign=m} exp(s_at[b,n]-colmax[b,m]) * qf[b][n][:]
__global__ __launch_bounds__(256) void k_update_gather(
    const int* __restrict__ assign, const float* __restrict__ s_at,
    const float* __restrict__ colmax, const u16* __restrict__ qf_hi,
    const u16* __restrict__ qf_lo, float* __restrict__ qu) {
  const int m = blockIdx.x;
  const int b = blockIdx.y;
  __shared__ int list[4096];
  __shared__ int cnt;
  const int tid = threadIdx.x;
  if (tid == 0) cnt = 0;
  __syncthreads();
  const int* ab = assign + b * N_;
  for (int n = tid; n < N_; n += 256) {
    if (ab[n] == m) { const int p = atomicAdd(&cnt, 1); list[p] = n; }
  }
  __syncthreads();
  const float cm = colmax[b * M_ + m];
  const int c0 = tid, c1 = tid + 256;
  float acc0 = 0.f, acc1 = 0.f;
  const int K = cnt;
  for (int i = 0; i < K; ++i) {
    const int n = list[i];
    const float w = expf(s_at[b * N_ + n] - cm);
    const u16* qh = qf_hi + ((size_t)b * N_ + n) * D_;
    const u16* ql = qf_lo + ((size_t)b * N_ + n) * D_;
    acc0 += w * (bf2f(qh[c0]) + bf2f(ql[c0]));
    acc1 += w * (bf2f(qh[c1]) + bf2f(ql[c1]));
  }
  float* orow = qu + ((size_t)b * M_ + m) * D_;
  orow[c0] = acc0;
  orow[c1] = acc1;
}

// K6: fused 8-step scan (rows independent): mem = l2norm(mem + qu_b), b=0..7
__global__ __launch_bounds__(256) void k_mem_fused(
    const float* __restrict__ keys, const float* __restrict__ qu,
    float* __restrict__ out1) {
  const int m = blockIdx.x, tid = threadIdx.x;
  const size_t base = (size_t)m * D_;
  float v0 = keys[base + tid], v1 = keys[base + tid + 256];
  __shared__ float red[256];
  for (int b = 0; b < B_; ++b) {
    const float* qb = qu + (size_t)b * M_ * D_ + base;
    v0 += qb[tid]; v1 += qb[tid + 256];
    red[tid] = v0 * v0 + v1 * v1;
    __syncthreads();
    for (int s = 128; s > 0; s >>= 1) {
      if (tid < s) red[tid] += red[tid + s];
      __syncthreads();
    }
    const float inv = 1.0f / fmaxf(sqrtf(red[0]), 1e-12f);
    v0 *= inv; v1 *= inv;
    __syncthreads();
  }
  out1[base + tid] = v0;
  out1[base + tid + 256] = v1;
}

// K7a: updated_query[:, :512, :, :] = q * inv_norm (elementwise, orig layout)
__global__ __launch_bounds__(256) void k_out_first(
    const float* __restrict__ q, const float* __restrict__ inv_nrm,
    float* __restrict__ out0) {
  const size_t i4 = (size_t)blockIdx.x * 256 + threadIdx.x;
  const size_t base = i4 * 4;
  const int n = (int)(base & 4095);
  const size_t bc = base >> 12;
  const size_t b = bc >> 9;
  const float4 v = *(const float4*)(q + base);
  const float4 w = *(const float4*)(inv_nrm + b * N_ + n);
  *(float4*)(out0 + ((bc + b * 512) << 12) + n) =
      make_float4(v.x * w.x, v.y * w.y, v.z * w.z, v.w * w.w);
}

// K7b: out0[b][512+d][n] = sum_m sm[b][n][m]*keysT[d][m], 3-term bf16 MFMA.
// A rows: in-place softmax rows (stride 1024 u16, hi at +0, lo at +512).
// Epilogue: stage C^T (d-major) in LDS, write 512B-contiguous n-runs.
__global__ __launch_bounds__(256, 2) void k_gemm_concat_mfma(
    const u16* __restrict__ smU, const u16* __restrict__ Bh_g,
    const u16* __restrict__ Bl_g, float* __restrict__ out0) {
  const int b = blockIdx.z;
  const int n0 = blockIdx.y * 128;
  const int d0b = blockIdx.x * 128;
  __shared__ __attribute__((aligned(16))) char smem[33792];
  u16* sA = (u16*)smem;          // [2][128][32]
  u16* sB = (u16*)smem + 8192;   // [2][128][32]
  float* stage = (float*)smem;   // [64][132]
  const int tid = threadIdx.x;
  const int lane = tid & 63;
  const int wave = tid >> 6;
  const int wr = wave >> 1, wc = wave & 1;
  const int frow = lane & 15;
  const int fchunk = lane >> 4;
  const int rchunk = fchunk ^ ((frow >> 1) & 3);
  const int r0 = tid >> 2, c0 = tid & 3, kc0 = c0 << 3;
  const int woff0 = lds_off(r0, c0);
  const int woff1 = lds_off(r0 + 64, c0);
  f4n acc[4][4] = {};
  const u16* Ab = smU + (size_t)b * N_ * 1024;
  const u16* Bg[2] = {Bh_g, Bl_g};
  int4 ra[2][2], rb[2][2];
#pragma unroll
  for (int hl = 0; hl < 2; ++hl) {
    const int off = hl * 512;
    ra[hl][0] = *(const int4*)(Ab + (size_t)(n0 + r0) * 1024 + off + kc0);
    ra[hl][1] = *(const int4*)(Ab + (size_t)(n0 + r0 + 64) * 1024 + off + kc0);
    rb[hl][0] = *(const int4*)(Bg[hl] + (size_t)(d0b + r0) * M_ + kc0);
    rb[hl][1] = *(const int4*)(Bg[hl] + (size_t)(d0b + r0 + 64) * M_ + kc0);
  }
  for (int k0 = 0; k0 < 512; k0 += 32) {
    __syncthreads();
#pragma unroll
    for (int hl = 0; hl < 2; ++hl) {
      *(int4*)(sA + hl * 4096 + woff0) = ra[hl][0];
      *(int4*)(sA + hl * 4096 + woff1) = ra[hl][1];
      *(int4*)(sB + hl * 4096 + woff0) = rb[hl][0];
      *(int4*)(sB + hl * 4096 + woff1) = rb[hl][1];
    }
    __syncthreads();
    const int kn = (k0 + 32) & 511;
#pragma unroll
    for (int hl = 0; hl < 2; ++hl) {
      const int off = hl * 512;
      ra[hl][0] = *(const int4*)(Ab + (size_t)(n0 + r0) * 1024 + off + kn + kc0);
      ra[hl][1] = *(const int4*)(Ab + (size_t)(n0 + r0 + 64) * 1024 + off + kn + kc0);
      rb[hl][0] = *(const int4*)(Bg[hl] + (size_t)(d0b + r0) * M_ + kn + kc0);
      rb[hl][1] = *(const int4*)(Bg[hl] + (size_t)(d0b + r0 + 64) * M_ + kn + kc0);
    }
    bf8 af[2][4], bfr[2][4];
#pragma unroll
    for (int i = 0; i < 4; ++i) {
      const int arow = wr * 64 + i * 16 + frow;
      const int brow = wc * 64 + i * 16 + frow;
      const int koff = rchunk << 3;
      af[0][i] = *(const bf8*)(sA + arow * 32 + koff);
      af[1][i] = *(const bf8*)(sA + 4096 + arow * 32 + koff);
      bfr[0][i] = *(const bf8*)(sB + brow * 32 + koff);
      bfr[1][i] = *(const bf8*)(sB + 4096 + brow * 32 + koff);
    }
#pragma unroll
    for (int i = 0; i < 4; ++i)
#pragma unroll
      for (int j = 0; j < 4; ++j) {
        acc[i][j] = __builtin_amdgcn_mfma_f32_16x16x32_bf16(af[0][i], bfr[0][j], acc[i][j], 0, 0, 0);
        acc[i][j] = __builtin_amdgcn_mfma_f32_16x16x32_bf16(af[0][i], bfr[1][j], acc[i][j], 0, 0, 0);
        acc[i][j] = __builtin_amdgcn_mfma_f32_16x16x32_bf16(af[1][i], bfr[0][j], acc[i][j], 0, 0, 0);
      }
  }
  // Epilogue: per d-half (wc==h), stage C^T[d_local][n_local] then write
  // each output d-row as one 512B-contiguous n-run.
  const int q4 = (lane >> 4) << 2;
#pragma unroll
  for (int h = 0; h < 2; ++h) {
    __syncthreads();
    if (wc == h) {
#pragma unroll
      for (int i = 0; i < 4; ++i)
#pragma unroll
        for (int j = 0; j < 4; ++j)
          *(f4n*)&stage[(j * 16 + frow) * 132 + wr * 64 + i * 16 + q4] = acc[i][j];
    }
    __syncthreads();
    float* obase = out0 + ((size_t)b * 1024 + 512 + d0b + 64 * h) * (size_t)HW_ + n0;
    const int cc = (tid & 31) << 2;
#pragma unroll
    for (int p = 0; p < 8; ++p) {
      const int row = p * 8 + (tid >> 5);
      *(f4n*)(obase + (size_t)row * HW_ + cc) = *(const f4n*)&stage[row * 132 + cc];
    }
  }
}

extern "C" void kernel_launch(void* const* d_in, const int* in_sizes, int n_in,
                              void* d_out, int out_size, void* d_ws, size_t ws_size,
                              hipStream_t stream) {
  const float* q = (const float*)d_in[0];     // [8,512,64,64]
  const float* keys = (const float*)d_in[1];  // [512,512]
  float* out = (float*)d_out;
  float* ws = (float*)d_ws;

  float* score    = ws;
  u16*   qf_hi    = (u16*)(ws + 16777216);
  u16*   qf_lo    = (u16*)(ws + 25165824);
  float* qu       = ws + 33554432;
  float* inv_nrm  = ws + 35651584;
  float* s_at     = ws + 35684352;
  float* colmax   = ws + 35717120;
  int*   assign   = (int*)(ws + 35721216);
  u16*   keys_hi  = (u16*)(ws + 35753984);
  u16*   keys_lo  = (u16*)(ws + 35885056);
  u16*   keysT_hi = (u16*)(ws + 36016128);
  u16*   keysT_lo = (u16*)(ws + 36147200);
  int*   fix_cnt  = (int*)(ws + 36278272);
  int*   fix_list = (int*)(ws + 36278273);

  float* out0 = out;             // updated_query  [8,1024,64,64]
  float* out1 = out + 33554432;  // updated_memory [512,512]
  float* out2 = out + 33816576;  // loss_separate  [8,4096]
  float* out3 = out + 33849344;  // loss_compact   [8,4096,512]
  float* out4 = out + 50626560;  // closest idx    [8,4096]

  k_split_keys<<<dim3(16, 16), 256, 0, stream>>>(keys, keys_hi, keys_lo,
                                                 keysT_hi, keysT_lo, fix_cnt);
  k_norm_transpose<<<dim3(N_ / 32, B_), 256, 0, stream>>>(q, qf_hi, qf_lo, inv_nrm);
  k_gemm_score_mfma<<<dim3(M_ / 128, N_ / 128, B_), 256, 0, stream>>>(
      qf_hi, qf_lo, keys_hi, keys_lo, score);
  k_colmax<<<dim3(M_ / 32, B_), 256, 0, stream>>>(score, colmax);
  k_softmax_top2<<<dim3(B_ * N_), 256, 0, stream>>>(score, qf_hi, qf_lo, keys,
                                                    out2, out3, out4, s_at,
                                                    assign, fix_cnt, fix_list);
  k_fixup<<<dim3(256), 256, 0, stream>>>(fix_cnt, fix_list, q, inv_nrm, keys,
                                         out2, out3, out4, s_at, assign);
  k_update_gather<<<dim3(M_, B_), 256, 0, stream>>>(assign, s_at, colmax,
                                                    qf_hi, qf_lo, qu);
  k_mem_fused<<<dim3(M_), 256, 0, stream>>>(keys, qu, out1);
  k_out_first<<<dim3((B_ * D_ * HW_ / 4) / 256), 256, 0, stream>>>(q, inv_nrm, out0);
  k_gemm_concat_mfma<<<dim3(D_ / 128, N_ / 128, B_), 256, 0, stream>>>(
      (const u16*)score, keysT_hi, keysT_lo, out0);
}

// Round 5
// 1083.760 us; speedup vs baseline: 1.0397x; 1.0341x over previous
//
#include <hip/hip_runtime.h>
#include <cstdint>
#include <cstddef>

#define B_  8
#define N_  4096   // H*W
#define M_  512    // memory slots
#define D_  512    // feature dim (= C)
#define HW_ 4096

#define FIX_EPS 4e-3f

typedef unsigned short u16;
typedef unsigned int   u32;
typedef short bf8 __attribute__((ext_vector_type(8)));
typedef float f4n __attribute__((ext_vector_type(4)));

__device__ __forceinline__ float bf2f(u16 u) {
  return __uint_as_float(((u32)u) << 16);
}
__device__ __forceinline__ void split_f32(float x, u16& hi, u16& lo) {
  const u32 xb = __float_as_uint(x);
  hi = (u16)(xb >> 16);
  const float hif = __uint_as_float(xb & 0xffff0000u);
  lo = (u16)(__float_as_uint(x - hif) >> 16);
}

// LDS tile addressing: row-major [row][BK=32 u16], XOR chunk swizzle (conflict
// free per R4 measurement: SQ_LDS_BANK_CONFLICT == 0).
__device__ __forceinline__ int lds_off(int row, int chunk) {
  return row * 32 + ((chunk ^ ((row >> 1) & 3)) << 3);
}

// XCD-sibling swizzle: 1024 blocks = x(4 tiles sharing the A-tile) * g(256).
// L = (g&7) + 8*(x + 4*(g>>3)) keeps L%8 (XCD under round-robin) equal for
// the 4 x-siblings so the shared A-tile is fetched once per XCD L2.
__device__ __forceinline__ void unswizzle(int bid, int& x, int& y, int& b) {
  const int low3 = bid & 7, rest = bid >> 3;
  x = rest & 3;
  const int g = low3 + ((rest >> 2) << 3);
  y = g & 31;
  b = g >> 5;
}

// -------- workspace layout (float offsets) --------
// score   : 0          [B,N,M] fp32 (raw; then in-place bf16 hi|lo softmax)
// qf_hi   : 16777216   [B,N,D] u16   qf_lo: 25165824
// qu      : 33554432   [B,M,D] fp32
// inv_nrm : 35651584   [B,N]
// s_at    : 35684352   [B,N]
// colmax  : 35717120   [B,M]
// assign  : 35721216   [B,N] int
// keys_hi : 35753984   keys_lo: 35885056   keysT_hi: 36016128  keysT_lo: 36147200
// fix_cnt : 36278272   (1 int)
// fix_list: 36278273   (32768 int)

// K0: split keys into bf16 hi/lo (+ transposed copies); zero fixup counter
__global__ __launch_bounds__(256) void k_split_keys(
    const float* __restrict__ keys, u16* __restrict__ kh, u16* __restrict__ kl,
    u16* __restrict__ kth, u16* __restrict__ ktl, int* __restrict__ fix_cnt) {
  if (blockIdx.x == 0 && blockIdx.y == 0 && threadIdx.x == 0) *fix_cnt = 0;
  __shared__ float t[32][33];
  const int d0 = blockIdx.x * 32, m0 = blockIdx.y * 32;
  const int tid = threadIdx.x, tx = tid & 31, ty = tid >> 5;
  for (int r = ty; r < 32; r += 8) {
    const float v = keys[(size_t)(m0 + r) * D_ + d0 + tx];
    t[r][tx] = v;
    u16 h, l; split_f32(v, h, l);
    kh[(size_t)(m0 + r) * D_ + d0 + tx] = h;
    kl[(size_t)(m0 + r) * D_ + d0 + tx] = l;
  }
  __syncthreads();
  for (int r = ty; r < 32; r += 8) {
    const float v = t[tx][r];  // keys[m0+tx][d0+r]
    u16 h, l; split_f32(v, h, l);
    kth[(size_t)(d0 + r) * M_ + m0 + tx] = h;
    ktl[(size_t)(d0 + r) * M_ + m0 + tx] = l;
  }
}

// K1: l2-normalize over channel + transpose [B,C,N] -> [B,N,C] as bf16 hi/lo
__global__ __launch_bounds__(256) void k_norm_transpose(
    const float* __restrict__ q, u16* __restrict__ qf_hi,
    u16* __restrict__ qf_lo, float* __restrict__ inv_nrm) {
  __shared__ float tile[32][513];
  __shared__ float red[8][32];
  __shared__ float sinv[32];
  const int b = blockIdx.y;
  const int n0 = blockIdx.x * 32;
  const int tid = threadIdx.x;
  const int tx = tid & 31, ty = tid >> 5;
  const float* qb = q + (size_t)b * D_ * HW_ + n0;
  float ss = 0.f;
  for (int c = ty; c < D_; c += 8) {
    const float v = qb[(size_t)c * HW_ + tx];
    tile[tx][c] = v;
    ss += v * v;
  }
  red[ty][tx] = ss;
  __syncthreads();
  if (ty == 0) {
    float s = 0.f;
#pragma unroll
    for (int r = 0; r < 8; ++r) s += red[r][tx];
    const float inv = 1.0f / fmaxf(sqrtf(s), 1e-12f);
    sinv[tx] = inv;
    inv_nrm[b * N_ + n0 + tx] = inv;
  }
  __syncthreads();
  u16* qh = qf_hi + ((size_t)b * N_ + n0) * D_;
  u16* ql = qf_lo + ((size_t)b * N_ + n0) * D_;
  for (int i = tid; i < 32 * D_; i += 256) {
    const int nl = i >> 9, c = i & 511;
    const float x = tile[nl][c] * sinv[nl];
    u16 h, l; split_f32(x, h, l);
    qh[(size_t)nl * D_ + c] = h;
    ql[(size_t)nl * D_ + c] = l;
  }
}

// K2: score = qf . keys^T via 3-term bf16 MFMA (hi*hi + hi*lo + lo*hi).
__global__ __launch_bounds__(256, 4) void k_gemm_score_mfma(
    const u16* __restrict__ Ah_g, const u16* __restrict__ Al_g,
    const u16* __restrict__ Bh_g, const u16* __restrict__ Bl_g,
    float* __restrict__ score) {
  int xt, yt, b;
  unswizzle(blockIdx.x, xt, yt, b);
  const int n0 = yt * 128;
  const int m0 = xt * 128;
  __shared__ __attribute__((aligned(16))) char smem[33792];
  u16* sA = (u16*)smem;          // [2][128][32]
  u16* sB = (u16*)smem + 8192;   // [2][128][32]
  float* stage = (float*)smem;   // [64][132] (reused after main loop)
  const int tid = threadIdx.x;
  const int lane = tid & 63;
  const int wave = tid >> 6;
  const int wr = wave >> 1, wc = wave & 1;
  const int frow = lane & 15;
  const int fchunk = lane >> 4;
  const int rchunk = fchunk ^ ((frow >> 1) & 3);
  const int r0 = tid >> 2, c0 = tid & 3, kc0 = c0 << 3;
  const int woff0 = lds_off(r0, c0);
  const int woff1 = lds_off(r0 + 64, c0);
  f4n acc[4][4] = {};
  const u16* Ag[2] = {Ah_g + (size_t)b * N_ * D_, Al_g + (size_t)b * N_ * D_};
  const u16* Bg[2] = {Bh_g, Bl_g};
  int4 ra[2][2], rb[2][2];
#pragma unroll
  for (int hl = 0; hl < 2; ++hl) {
    ra[hl][0] = *(const int4*)(Ag[hl] + (size_t)(n0 + r0) * D_ + kc0);
    ra[hl][1] = *(const int4*)(Ag[hl] + (size_t)(n0 + r0 + 64) * D_ + kc0);
    rb[hl][0] = *(const int4*)(Bg[hl] + (size_t)(m0 + r0) * D_ + kc0);
    rb[hl][1] = *(const int4*)(Bg[hl] + (size_t)(m0 + r0 + 64) * D_ + kc0);
  }
  for (int d0 = 0; d0 < 512; d0 += 32) {
    __syncthreads();
#pragma unroll
    for (int hl = 0; hl < 2; ++hl) {
      *(int4*)(sA + hl * 4096 + woff0) = ra[hl][0];
      *(int4*)(sA + hl * 4096 + woff1) = ra[hl][1];
      *(int4*)(sB + hl * 4096 + woff0) = rb[hl][0];
      *(int4*)(sB + hl * 4096 + woff1) = rb[hl][1];
    }
    __syncthreads();
    const int dn = (d0 + 32) & 511;
#pragma unroll
    for (int hl = 0; hl < 2; ++hl) {
      ra[hl][0] = *(const int4*)(Ag[hl] + (size_t)(n0 + r0) * D_ + dn + kc0);
      ra[hl][1] = *(const int4*)(Ag[hl] + (size_t)(n0 + r0 + 64) * D_ + dn + kc0);
      rb[hl][0] = *(const int4*)(Bg[hl] + (size_t)(m0 + r0) * D_ + dn + kc0);
      rb[hl][1] = *(const int4*)(Bg[hl] + (size_t)(m0 + r0 + 64) * D_ + dn + kc0);
    }
    bf8 af[2][4], bfr[2][4];
#pragma unroll
    for (int i = 0; i < 4; ++i) {
      const int arow = wr * 64 + i * 16 + frow;
      const int brow = wc * 64 + i * 16 + frow;
      const int koff = rchunk << 3;
      af[0][i] = *(const bf8*)(sA + arow * 32 + koff);
      af[1][i] = *(const bf8*)(sA + 4096 + arow * 32 + koff);
      bfr[0][i] = *(const bf8*)(sB + brow * 32 + koff);
      bfr[1][i] = *(const bf8*)(sB + 4096 + brow * 32 + koff);
    }
#pragma unroll
    for (int i = 0; i < 4; ++i)
#pragma unroll
      for (int j = 0; j < 4; ++j) {
        acc[i][j] = __builtin_amdgcn_mfma_f32_16x16x32_bf16(af[0][i], bfr[0][j], acc[i][j], 0, 0, 0);
        acc[i][j] = __builtin_amdgcn_mfma_f32_16x16x32_bf16(af[0][i], bfr[1][j], acc[i][j], 0, 0, 0);
        acc[i][j] = __builtin_amdgcn_mfma_f32_16x16x32_bf16(af[1][i], bfr[0][j], acc[i][j], 0, 0, 0);
      }
  }
  // Epilogue: per n-half, stage 64x128 C in LDS then write 512B-contiguous.
  const int q4 = (lane >> 4) << 2;
#pragma unroll
  for (int h = 0; h < 2; ++h) {
    __syncthreads();
    if (wr == h) {
#pragma unroll
      for (int i = 0; i < 4; ++i)
#pragma unroll
        for (int j = 0; j < 4; ++j)
#pragma unroll
          for (int r = 0; r < 4; ++r)
            stage[(i * 16 + q4 + r) * 132 + wc * 64 + j * 16 + frow] = acc[i][j][r];
    }
    __syncthreads();
    float* Crow = score + ((size_t)b * N_ + n0 + 64 * h) * M_ + m0;
    const int cc = (tid & 31) << 2;
#pragma unroll
    for (int p = 0; p < 8; ++p) {
      const int row = p * 8 + (tid >> 5);
      *(f4n*)(Crow + (size_t)row * M_ + cc) = *(const f4n*)&stage[row * 132 + cc];
    }
  }
}

// K3: colmax[b][m] = max_n score[b][n][m]  (before in-place softmax overwrite)
__global__ __launch_bounds__(256) void k_colmax(
    const float* __restrict__ score, float* __restrict__ colmax) {
  const int b = blockIdx.y, m0 = blockIdx.x * 32;
  const int tid = threadIdx.x, tx = tid & 31, ty = tid >> 5;
  const float* sb = score + (size_t)b * N_ * M_ + m0 + tx;
  float mx = -1e30f;
  for (int n = ty; n < N_; n += 8) mx = fmaxf(mx, sb[(size_t)n * M_]);
  __shared__ float red[8][33];
  red[ty][tx] = mx;
  __syncthreads();
  if (ty == 0) {
#pragma unroll
    for (int r = 1; r < 8; ++r) mx = fmaxf(mx, red[r][tx]);
    colmax[b * M_ + m0 + tx] = mx;
  }
}

// K4: per (b,n) row: top-2 + third-max, near-tie flagging, softmax over m
//     written in place as bf16 hi|lo, triplet losses, s_at, assign
__global__ __launch_bounds__(256) void k_softmax_top2(
    float* __restrict__ score, const u16* __restrict__ qf_hi,
    const u16* __restrict__ qf_lo, const float* __restrict__ keys,
    float* __restrict__ out2, float* __restrict__ out3,
    float* __restrict__ out4, float* __restrict__ s_at,
    int* __restrict__ assign, int* __restrict__ fix_cnt,
    int* __restrict__ fix_list) {
  const int bn = blockIdx.x;
  const int tid = threadIdx.x;
  float* row = score + (size_t)bn * M_;
  const float v0 = row[tid];
  const float v1 = row[tid + 256];
  float t1v, t2v; int t1i, t2i;
  if (v0 >= v1) { t1v = v0; t1i = tid;       t2v = v1; t2i = tid + 256; }
  else          { t1v = v1; t1i = tid + 256; t2v = v0; t2i = tid; }
  __shared__ float sv1[256], sv2[256];
  __shared__ int   si1[256], si2[256];
  sv1[tid] = t1v; si1[tid] = t1i; sv2[tid] = t2v; si2[tid] = t2i;
  __syncthreads();
  for (int s = 128; s > 0; s >>= 1) {
    if (tid < s) {
      const float a1 = sv1[tid];     const int a1i = si1[tid];
      const float a2 = sv2[tid];     const int a2i = si2[tid];
      const float b1 = sv1[tid + s]; const int b1i = si1[tid + s];
      const float b2 = sv2[tid + s]; const int b2i = si2[tid + s];
      if (b1 > a1 || (b1 == a1 && b1i < a1i)) {
        float n2; int n2i;
        if (a1 > b2 || (a1 == b2 && a1i < b2i)) { n2 = a1; n2i = a1i; }
        else                                    { n2 = b2; n2i = b2i; }
        sv1[tid] = b1; si1[tid] = b1i; sv2[tid] = n2; si2[tid] = n2i;
      } else {
        if (b1 > a2 || (b1 == a2 && b1i < a2i)) { sv2[tid] = b1; si2[tid] = b1i; }
      }
    }
    __syncthreads();
  }
  const float rowmax = sv1[0];
  const float second = sv2[0];
  const int i1 = si1[0];
  const int i2 = si2[0];
  __syncthreads();
  // third max (excluding i1, i2) -> near-tie flag
  float m3 = -1e30f;
  if (tid != i1 && tid != i2) m3 = v0;
  if (tid + 256 != i1 && tid + 256 != i2) m3 = fmaxf(m3, v1);
  sv1[tid] = m3;
  __syncthreads();
  for (int s = 128; s > 0; s >>= 1) {
    if (tid < s) sv1[tid] = fmaxf(sv1[tid], sv1[tid + s]);
    __syncthreads();
  }
  if (tid == 0) {
    const float third = sv1[0];
    if (rowmax - second < FIX_EPS || second - third < FIX_EPS) {
      const int p = atomicAdd(fix_cnt, 1);
      fix_list[p] = bn;
    }
  }
  __syncthreads();
  const float e0 = expf(v0 - rowmax), e1 = expf(v1 - rowmax);
  sv1[tid] = e0 + e1;
  __syncthreads();
  for (int s = 128; s > 0; s >>= 1) {
    if (tid < s) sv1[tid] += sv1[tid + s];
    __syncthreads();
  }
  const float invsum = 1.0f / sv1[0];
  u16* rowU = (u16*)row;
  const float p0 = e0 * invsum, p1 = e1 * invsum;
  u16 h, l;
  split_f32(p0, h, l); rowU[tid] = h;       rowU[512 + tid] = l;
  split_f32(p1, h, l); rowU[tid + 256] = h; rowU[768 + tid] = l;
  __syncthreads();
  const u16* qh = qf_hi + (size_t)bn * D_;
  const u16* ql = qf_lo + (size_t)bn * D_;
  const float* pos = keys + (size_t)i1 * D_;
  const float* neg = keys + (size_t)i2 * D_;
  float* lc = out3 + (size_t)bn * D_;
  float dp = 0.f, dn = 0.f;
  for (int c = tid; c < D_; c += 256) {
    const float qv = bf2f(qh[c]) + bf2f(ql[c]);
    const float dP = qv - pos[c];
    lc[c] = dP * dP;
    const float a = dP + 1e-6f;
    dp += a * a;
    const float bb = (qv - neg[c]) + 1e-6f;
    dn += bb * bb;
  }
  sv1[tid] = dp; sv2[tid] = dn;
  __syncthreads();
  for (int s = 128; s > 0; s >>= 1) {
    if (tid < s) { sv1[tid] += sv1[tid + s]; sv2[tid] += sv2[tid + s]; }
    __syncthreads();
  }
  if (tid == 0) {
    out2[bn] = fmaxf(sqrtf(sv1[0]) - sqrtf(sv2[0]) + 1.0f, 0.0f);
    out4[bn] = (float)i1;
    s_at[bn] = rowmax;
    assign[bn] = i1;
  }
}

// K4b: exact fp32 re-score for flagged near-tie rows; rewrites losses/indices
__global__ __launch_bounds__(256) void k_fixup(
    const int* __restrict__ fix_cnt, const int* __restrict__ fix_list,
    const float* __restrict__ q, const float* __restrict__ inv_nrm,
    const float* __restrict__ keys, float* __restrict__ out2,
    float* __restrict__ out3, float* __restrict__ out4,
    float* __restrict__ s_at, int* __restrict__ assign) {
  const int cnt = *fix_cnt;
  const int tid = threadIdx.x;
  __shared__ float qrow[512];
  __shared__ float sv1[256], sv2[256];
  __shared__ int   si1[256], si2[256];
  for (int idx = blockIdx.x; idx < cnt; idx += gridDim.x) {
    const int bn = fix_list[idx];
    const int b = bn >> 12;
    const int n = bn & 4095;
    const float inv = inv_nrm[bn];
    for (int c = tid; c < 512; c += 256)
      qrow[c] = q[((size_t)b * D_ + c) * (size_t)HW_ + n] * inv;
    __syncthreads();
    float sc0 = 0.f, sc1 = 0.f;
    const float* k0 = keys + (size_t)tid * D_;
    const float* k1 = keys + (size_t)(tid + 256) * D_;
    for (int d = 0; d < 512; ++d) {
      const float qv = qrow[d];
      sc0 = fmaf(qv, k0[d], sc0);
      sc1 = fmaf(qv, k1[d], sc1);
    }
    float t1v, t2v; int t1i, t2i;
    if (sc0 >= sc1) { t1v = sc0; t1i = tid;       t2v = sc1; t2i = tid + 256; }
    else            { t1v = sc1; t1i = tid + 256; t2v = sc0; t2i = tid; }
    sv1[tid] = t1v; si1[tid] = t1i; sv2[tid] = t2v; si2[tid] = t2i;
    __syncthreads();
    for (int s = 128; s > 0; s >>= 1) {
      if (tid < s) {
        const float a1 = sv1[tid];     const int a1i = si1[tid];
        const float a2 = sv2[tid];     const int a2i = si2[tid];
        const float b1 = sv1[tid + s]; const int b1i = si1[tid + s];
        const float b2 = sv2[tid + s]; const int b2i = si2[tid + s];
        if (b1 > a1 || (b1 == a1 && b1i < a1i)) {
          float n2; int n2i;
          if (a1 > b2 || (a1 == b2 && a1i < b2i)) { n2 = a1; n2i = a1i; }
          else                                    { n2 = b2; n2i = b2i; }
          sv1[tid] = b1; si1[tid] = b1i; sv2[tid] = n2; si2[tid] = n2i;
        } else {
          if (b1 > a2 || (b1 == a2 && b1i < a2i)) { sv2[tid] = b1; si2[tid] = b1i; }
        }
      }
      __syncthreads();
    }
    const float rowmax = sv1[0];
    const int i1 = si1[0];
    const int i2 = si2[0];
    __syncthreads();
    const float* pos = keys + (size_t)i1 * D_;
    const float* neg = keys + (size_t)i2 * D_;
    float* lc = out3 + (size_t)bn * D_;
    float dp = 0.f, dn = 0.f;
    for (int c = tid; c < D_; c += 256) {
      const float qv = qrow[c];
      const float dP = qv - pos[c];
      lc[c] = dP * dP;
      const float a = dP + 1e-6f;
      dp += a * a;
      const float bb = (qv - neg[c]) + 1e-6f;
      dn += bb * bb;
    }
    sv1[tid] = dp; sv2[tid] = dn;
    __syncthreads();
    for (int s = 128; s > 0; s >>= 1) {
      if (tid < s) { sv1[tid] += sv1[tid + s]; sv2[tid] += sv2[tid + s]; }
      __syncthreads();
    }
    if (tid == 0) {
      out2[bn] = fmaxf(sqrtf(sv1[0]) - sqrtf(sv2[0]) + 1.0f, 0.0f);
      out4[bn] = (float)i1;
      s_at[bn] = rowmax;
      assign[bn] = i1;
    }
    __syncthreads();
  }
}

// K5: qu[b][m][:] = sum_{n: assign=m} exp(s_at[b,n]-colmax[b,m]) * qf[b][n][:]
__global__ __launch_bounds__(256) void k_update_gather(
    const int* __restrict__ assign, const float* __restrict__ s_at,
    const float* __restrict__ colmax, const u16* __restrict__ qf_hi,
    const u16* __restrict__ qf_lo, float* __restrict__ qu) {
  const int m = blockIdx.x;
  const int b = blockIdx.y;
  __shared__ int list[4096];
  __shared__ int cnt;
  const int tid = threadIdx.x;
  if (tid == 0) cnt = 0;
  __syncthreads();
  const int* ab = assign + b * N_;
  for (int n = tid; n < N_; n += 256) {
    if (ab[n] == m) { const int p = atomicAdd(&cnt, 1); list[p] = n; }
  }
  __syncthreads();
  const float cm = colmax[b * M_ + m];
  const int c0 = tid, c1 = tid + 256;
  float acc0 = 0.f, acc1 = 0.f;
  const int K = cnt;
  for (int i = 0; i < K; ++i) {
    const int n = list[i];
    const float w = expf(s_at[b * N_ + n] - cm);
    const u16* qh = qf_hi + ((size_t)b * N_ + n) * D_;
    const u16* ql = qf_lo + ((size_t)b * N_ + n) * D_;
    acc0 += w * (bf2f(qh[c0]) + bf2f(ql[c0]));
    acc1 += w * (bf2f(qh[c1]) + bf2f(ql[c1]));
  }
  float* orow = qu + ((size_t)b * M_ + m) * D_;
  orow[c0] = acc0;
  orow[c1] = acc1;
}

// K6: fused 8-step scan (rows independent): mem = l2norm(mem + qu_b), b=0..7
__global__ __launch_bounds__(256) void k_mem_fused(
    const float* __restrict__ keys, const float* __restrict__ qu,
    float* __restrict__ out1) {
  const int m = blockIdx.x, tid = threadIdx.x;
  const size_t base = (size_t)m * D_;
  float v0 = keys[base + tid], v1 = keys[base + tid + 256];
  __shared__ float red[256];
  for (int b = 0; b < B_; ++b) {
    const float* qb = qu + (size_t)b * M_ * D_ + base;
    v0 += qb[tid]; v1 += qb[tid + 256];
    red[tid] = v0 * v0 + v1 * v1;
    __syncthreads();
    for (int s = 128; s > 0; s >>= 1) {
      if (tid < s) red[tid] += red[tid + s];
      __syncthreads();
    }
    const float inv = 1.0f / fmaxf(sqrtf(red[0]), 1e-12f);
    v0 *= inv; v1 *= inv;
    __syncthreads();
  }
  out1[base + tid] = v0;
  out1[base + tid + 256] = v1;
}

// K7a: updated_query[:, :512, :, :] = q * inv_norm (elementwise, orig layout)
__global__ __launch_bounds__(256) void k_out_first(
    const float* __restrict__ q, const float* __restrict__ inv_nrm,
    float* __restrict__ out0) {
  const size_t i4 = (size_t)blockIdx.x * 256 + threadIdx.x;
  const size_t base = i4 * 4;
  const int n = (int)(base & 4095);
  const size_t bc = base >> 12;
  const size_t b = bc >> 9;
  const float4 v = *(const float4*)(q + base);
  const float4 w = *(const float4*)(inv_nrm + b * N_ + n);
  const f4n r = {v.x * w.x, v.y * w.y, v.z * w.z, v.w * w.w};
  __builtin_nontemporal_store(r, (f4n*)(out0 + ((bc + b * 512) << 12) + n));
}

// K7b: out0[b][512+d][n] = sum_m sm[b][n][m]*keysT[d][m], 3-term bf16 MFMA.
// A rows: in-place softmax rows (stride 1024 u16, hi at +0, lo at +512).
// Epilogue: stage C^T (d-major) in LDS, nontemporal 512B-contiguous n-runs.
__global__ __launch_bounds__(256, 4) void k_gemm_concat_mfma(
    const u16* __restrict__ smU, const u16* __restrict__ Bh_g,
    const u16* __restrict__ Bl_g, float* __restrict__ out0) {
  int xt, yt, b;
  unswizzle(blockIdx.x, xt, yt, b);
  const int n0 = yt * 128;
  const int d0b = xt * 128;
  __shared__ __attribute__((aligned(16))) char smem[33792];
  u16* sA = (u16*)smem;          // [2][128][32]
  u16* sB = (u16*)smem + 8192;   // [2][128][32]
  float* stage = (float*)smem;   // [64][132]
  const int tid = threadIdx.x;
  const int lane = tid & 63;
  const int wave = tid >> 6;
  const int wr = wave >> 1, wc = wave & 1;
  const int frow = lane & 15;
  const int fchunk = lane >> 4;
  const int rchunk = fchunk ^ ((frow >> 1) & 3);
  const int r0 = tid >> 2, c0 = tid & 3, kc0 = c0 << 3;
  const int woff0 = lds_off(r0, c0);
  const int woff1 = lds_off(r0 + 64, c0);
  f4n acc[4][4] = {};
  const u16* Ab = smU + (size_t)b * N_ * 1024;
  const u16* Bg[2] = {Bh_g, Bl_g};
  int4 ra[2][2], rb[2][2];
#pragma unroll
  for (int hl = 0; hl < 2; ++hl) {
    const int off = hl * 512;
    ra[hl][0] = *(const int4*)(Ab + (size_t)(n0 + r0) * 1024 + off + kc0);
    ra[hl][1] = *(const int4*)(Ab + (size_t)(n0 + r0 + 64) * 1024 + off + kc0);
    rb[hl][0] = *(const int4*)(Bg[hl] + (size_t)(d0b + r0) * M_ + kc0);
    rb[hl][1] = *(const int4*)(Bg[hl] + (size_t)(d0b + r0 + 64) * M_ + kc0);
  }
  for (int k0 = 0; k0 < 512; k0 += 32) {
    __syncthreads();
#pragma unroll
    for (int hl = 0; hl < 2; ++hl) {
      *(int4*)(sA + hl * 4096 + woff0) = ra[hl][0];
      *(int4*)(sA + hl * 4096 + woff1) = ra[hl][1];
      *(int4*)(sB + hl * 4096 + woff0) = rb[hl][0];
      *(int4*)(sB + hl * 4096 + woff1) = rb[hl][1];
    }
    __syncthreads();
    const int kn = (k0 + 32) & 511;
#pragma unroll
    for (int hl = 0; hl < 2; ++hl) {
      const int off = hl * 512;
      ra[hl][0] = *(const int4*)(Ab + (size_t)(n0 + r0) * 1024 + off + kn + kc0);
      ra[hl][1] = *(const int4*)(Ab + (size_t)(n0 + r0 + 64) * 1024 + off + kn + kc0);
      rb[hl][0] = *(const int4*)(Bg[hl] + (size_t)(d0b + r0) * M_ + kn + kc0);
      rb[hl][1] = *(const int4*)(Bg[hl] + (size_t)(d0b + r0 + 64) * M_ + kn + kc0);
    }
    bf8 af[2][4], bfr[2][4];
#pragma unroll
    for (int i = 0; i < 4; ++i) {
      const int arow = wr * 64 + i * 16 + frow;
      const int brow = wc * 64 + i * 16 + frow;
      const int koff = rchunk << 3;
      af[0][i] = *(const bf8*)(sA + arow * 32 + koff);
      af[1][i] = *(const bf8*)(sA + 4096 + arow * 32 + koff);
      bfr[0][i] = *(const bf8*)(sB + brow * 32 + koff);
      bfr[1][i] = *(const bf8*)(sB + 4096 + brow * 32 + koff);
    }
#pragma unroll
    for (int i = 0; i < 4; ++i)
#pragma unroll
      for (int j = 0; j < 4; ++j) {
        acc[i][j] = __builtin_amdgcn_mfma_f32_16x16x32_bf16(af[0][i], bfr[0][j], acc[i][j], 0, 0, 0);
        acc[i][j] = __builtin_amdgcn_mfma_f32_16x16x32_bf16(af[0][i], bfr[1][j], acc[i][j], 0, 0, 0);
        acc[i][j] = __builtin_amdgcn_mfma_f32_16x16x32_bf16(af[1][i], bfr[0][j], acc[i][j], 0, 0, 0);
      }
  }
  const int q4 = (lane >> 4) << 2;
#pragma unroll
  for (int h = 0; h < 2; ++h) {
    __syncthreads();
    if (wc == h) {
#pragma unroll
      for (int i = 0; i < 4; ++i)
#pragma unroll
        for (int j = 0; j < 4; ++j)
          *(f4n*)&stage[(j * 16 + frow) * 132 + wr * 64 + i * 16 + q4] = acc[i][j];
    }
    __syncthreads();
    float* obase = out0 + ((size_t)b * 1024 + 512 + d0b + 64 * h) * (size_t)HW_ + n0;
    const int cc = (tid & 31) << 2;
#pragma unroll
    for (int p = 0; p < 8; ++p) {
      const int row = p * 8 + (tid >> 5);
      const f4n v = *(const f4n*)&stage[row * 132 + cc];
      __builtin_nontemporal_store(v, (f4n*)(obase + (size_t)row * HW_ + cc));
    }
  }
}

extern "C" void kernel_launch(void* const* d_in, const int* in_sizes, int n_in,
                              void* d_out, int out_size, void* d_ws, size_t ws_size,
                              hipStream_t stream) {
  const float* q = (const float*)d_in[0];     // [8,512,64,64]
  const float* keys = (const float*)d_in[1];  // [512,512]
  float* out = (float*)d_out;
  float* ws = (float*)d_ws;

  float* score    = ws;
  u16*   qf_hi    = (u16*)(ws + 16777216);
  u16*   qf_lo    = (u16*)(ws + 25165824);
  float* qu       = ws + 33554432;
  float* inv_nrm  = ws + 35651584;
  float* s_at     = ws + 35684352;
  float* colmax   = ws + 35717120;
  int*   assign   = (int*)(ws + 35721216);
  u16*   keys_hi  = (u16*)(ws + 35753984);
  u16*   keys_lo  = (u16*)(ws + 35885056);
  u16*   keysT_hi = (u16*)(ws + 36016128);
  u16*   keysT_lo = (u16*)(ws + 36147200);
  int*   fix_cnt  = (int*)(ws + 36278272);
  int*   fix_list = (int*)(ws + 36278273);

  float* out0 = out;             // updated_query  [8,1024,64,64]
  float* out1 = out + 33554432;  // updated_memory [512,512]
  float* out2 = out + 33816576;  // loss_separate  [8,4096]
  float* out3 = out + 33849344;  // loss_compact   [8,4096,512]
  float* out4 = out + 50626560;  // closest idx    [8,4096]

  k_split_keys<<<dim3(16, 16), 256, 0, stream>>>(keys, keys_hi, keys_lo,
                                                 keysT_hi, keysT_lo, fix_cnt);
  k_norm_transpose<<<dim3(N_ / 32, B_), 256, 0, stream>>>(q, qf_hi, qf_lo, inv_nrm);
  k_gemm_score_mfma<<<dim3(1024), 256, 0, stream>>>(qf_hi, qf_lo, keys_hi,
                                                    keys_lo, score);
  k_colmax<<<dim3(M_ / 32, B_), 256, 0, stream>>>(score, colmax);
  k_softmax_top2<<<dim3(B_ * N_), 256, 0, stream>>>(score, qf_hi, qf_lo, keys,
                                                    out2, out3, out4, s_at,
                                                    assign, fix_cnt, fix_list);
  k_fixup<<<dim3(256), 256, 0, stream>>>(fix_cnt, fix_list, q, inv_nrm, keys,
                                         out2, out3, out4, s_at, assign);
  k_update_gather<<<dim3(M_, B_), 256, 0, stream>>>(assign, s_at, colmax,
                                                    qf_hi, qf_lo, qu);
  k_mem_fused<<<dim3(M_), 256, 0, stream>>>(keys, qu, out1);
  k_out_first<<<dim3((B_ * D_ * HW_ / 4) / 256), 256, 0, stream>>>(q, inv_nrm, out0);
  k_gemm_concat_mfma<<<dim3(1024), 256, 0, stream>>>((const u16*)score,
                                                     keysT_hi, keysT_lo, out0);
}